// Round 4
// baseline (256.360 us; speedup 1.0000x reference)
//
#include <hip/hip_runtime.h>

// Problem constants (from reference setup_inputs)
#define NN 15828      // nodes
#define NE 253248     // edges (divisible by 4)
#define BB 64         // batch == wavefront size
#define HID 100       // hidden
#define NC 10         // classes
#define NEG 0.01f     // leaky slope

__device__ __forceinline__ float leaky(float v) { return v > 0.f ? v : NEG * v; }
__device__ __forceinline__ float rsq(int c) { return rsqrtf((float)(c > 1 ? c : 1)); }

// -------------------------- degree count: 4 edges per thread via int4 loads
__global__ void k_count(const int* __restrict__ src, const int* __restrict__ dst,
                        int* __restrict__ cnt_out, int* __restrict__ cnt_in) {
    int e = (blockIdx.x * blockDim.x + threadIdx.x) * 4;
    if (e < NE) {
        int4 s = *(const int4*)(src + e);
        int4 d = *(const int4*)(dst + e);
        atomicAdd(&cnt_out[s.x], 1); atomicAdd(&cnt_out[s.y], 1);
        atomicAdd(&cnt_out[s.z], 1); atomicAdd(&cnt_out[s.w], 1);
        atomicAdd(&cnt_in[d.x], 1);  atomicAdd(&cnt_in[d.y], 1);
        atomicAdd(&cnt_in[d.z], 1);  atomicAdd(&cnt_in[d.w], 1);
    }
}

// ------- conv0 scatter: s0[dst,b] += feat[src,b] * rsqrt(deg_out[src])
// one wave per 4 edges; lane = batch. Reads/atomics fully coalesced (256B).
__global__ void k_scat0(const int* __restrict__ src, const int* __restrict__ dst,
                        const int* __restrict__ cnt_out,
                        const float* __restrict__ feat, float* __restrict__ s0) {
    int wid = (blockIdx.x * blockDim.x + threadIdx.x) >> 6;  // grid exact: NE/4 waves
    int lane = threadIdx.x & 63;
    int e0 = wid * 4;
    int4 s4 = *(const int4*)(src + e0);
    int4 d4 = *(const int4*)(dst + e0);
    float r0 = rsq(cnt_out[s4.x]), r1 = rsq(cnt_out[s4.y]);
    float r2 = rsq(cnt_out[s4.z]), r3 = rsq(cnt_out[s4.w]);
    float f0 = feat[(s4.x << 6) + lane] * r0;
    float f1 = feat[(s4.y << 6) + lane] * r1;
    float f2 = feat[(s4.z << 6) + lane] * r2;
    float f3 = feat[(s4.w << 6) + lane] * r3;
    atomicAdd(&s0[(d4.x << 6) + lane], f0);
    atomicAdd(&s0[(d4.y << 6) + lane], f1);
    atomicAdd(&s0[(d4.z << 6) + lane], f2);
    atomicAdd(&s0[(d4.w << 6) + lane], f3);
}

// --- pointwise: y[n,b] = rsqrt(deg_out[n]) * sum_f leaky(ci*s0*W0[f]+b0[f])*W1[f]
// also emits ci[n] = rsqrt(deg_in[n]) for the gemm's on-the-fly h1.
__global__ void k_pw(const float* __restrict__ s0,
                     const int* __restrict__ cnt_out, const int* __restrict__ cnt_in,
                     const float* __restrict__ W0, const float* __restrict__ b0,
                     const float* __restrict__ W1,
                     float* __restrict__ y, float* __restrict__ ci_arr) {
    __shared__ __align__(16) float w0s[HID], b0s[HID], w1s[HID];
    int tid = threadIdx.x;
    if (tid < HID) { w0s[tid] = W0[tid]; b0s[tid] = b0[tid]; w1s[tid] = W1[tid]; }
    __syncthreads();
    int i = blockIdx.x * blockDim.x + tid;   // grid exact NN*BB/256
    int n = i >> 6, lane = i & 63;
    float ci = rsq(cnt_in[n]);
    float t = s0[i] * ci;
    float acc = 0.f;
#pragma unroll
    for (int f = 0; f < HID; f += 4) {
        float4 w0v = *(const float4*)&w0s[f];
        float4 b0v = *(const float4*)&b0s[f];
        float4 w1v = *(const float4*)&w1s[f];
        float v0 = fmaf(t, w0v.x, b0v.x); v0 = v0 > 0.f ? v0 : NEG * v0; acc = fmaf(v0, w1v.x, acc);
        float v1 = fmaf(t, w0v.y, b0v.y); v1 = v1 > 0.f ? v1 : NEG * v1; acc = fmaf(v1, w1v.y, acc);
        float v2 = fmaf(t, w0v.z, b0v.z); v2 = v2 > 0.f ? v2 : NEG * v2; acc = fmaf(v2, w1v.z, acc);
        float v3 = fmaf(t, w0v.w, b0v.w); v3 = v3 > 0.f ? v3 : NEG * v3; acc = fmaf(v3, w1v.w, acc);
    }
    y[i] = acc * rsq(cnt_out[n]);
    if (lane == 0) ci_arr[n] = ci;
}

// ------- conv1 scatter: z1[dst,b] += y[src,b]
__global__ void k_scat1(const int* __restrict__ src, const int* __restrict__ dst,
                        const float* __restrict__ y, float* __restrict__ z1) {
    int wid = (blockIdx.x * blockDim.x + threadIdx.x) >> 6;  // grid exact: NE/4 waves
    int lane = threadIdx.x & 63;
    int e0 = wid * 4;
    int4 s4 = *(const int4*)(src + e0);
    int4 d4 = *(const int4*)(dst + e0);
    float f0 = y[(s4.x << 6) + lane];
    float f1 = y[(s4.y << 6) + lane];
    float f2 = y[(s4.z << 6) + lane];
    float f3 = y[(s4.w << 6) + lane];
    atomicAdd(&z1[(d4.x << 6) + lane], f0);
    atomicAdd(&z1[(d4.y << 6) + lane], f1);
    atomicAdd(&z1[(d4.z << 6) + lane], f2);
    atomicAdd(&z1[(d4.w << 6) + lane], f3);
}

// ------- split-K GEMM, h1 computed on the fly:
//   h1[n,b] = leaky(ci[n]*z1[n,b] + b1)
//   out1acc[f*64+b] += sum_{n in chunk} h1[n,b]*lw0[f,n]   (atomic epilogue)
// block = 4 waves; each wave computes 4 consecutive f rows.
#define NSPLIT 128
#define NCHUNK 124   // 128*124 = 15872 >= 15828; chunk length divisible by 4
__global__ void k_gemm(const float* __restrict__ z1, const float* __restrict__ ci,
                       const float* __restrict__ b1, const float* __restrict__ lw0,
                       float* __restrict__ out1acc) {
    int lane = threadIdx.x & 63;
    int w = threadIdx.x >> 6;
    int f0 = blockIdx.x * 16 + w * 4;     // 0,4,...,108
    int s = blockIdx.y;                   // 0..127
    if (f0 >= HID) return;
    int n0 = s * NCHUNK;
    int n1 = min(NN, n0 + NCHUNK);
    float bb1 = b1[0];
    const float* zp  = z1 + (size_t)n0 * BB + lane;
    const float* w0p = lw0 + (size_t)(f0 + 0) * NN;
    const float* w1p = lw0 + (size_t)(f0 + 1) * NN;
    const float* w2p = lw0 + (size_t)(f0 + 2) * NN;
    const float* w3p = lw0 + (size_t)(f0 + 3) * NN;
    float a0 = 0.f, a1 = 0.f, a2 = 0.f, a3 = 0.f;
    for (int n = n0; n < n1; n += 4) {
        float4 civ = *(const float4*)(ci + n);
        float4 wa = *(const float4*)(w0p + n);
        float4 wb = *(const float4*)(w1p + n);
        float4 wc = *(const float4*)(w2p + n);
        float4 wd = *(const float4*)(w3p + n);
        float h0 = leaky(fmaf(civ.x, zp[0],   bb1));
        float h1 = leaky(fmaf(civ.y, zp[64],  bb1));
        float h2 = leaky(fmaf(civ.z, zp[128], bb1));
        float h3 = leaky(fmaf(civ.w, zp[192], bb1));
        a0 = fmaf(h0, wa.x, a0); a1 = fmaf(h0, wb.x, a1); a2 = fmaf(h0, wc.x, a2); a3 = fmaf(h0, wd.x, a3);
        a0 = fmaf(h1, wa.y, a0); a1 = fmaf(h1, wb.y, a1); a2 = fmaf(h1, wc.y, a2); a3 = fmaf(h1, wd.y, a3);
        a0 = fmaf(h2, wa.z, a0); a1 = fmaf(h2, wb.z, a1); a2 = fmaf(h2, wc.z, a2); a3 = fmaf(h2, wd.z, a3);
        a0 = fmaf(h3, wa.w, a0); a1 = fmaf(h3, wb.w, a1); a2 = fmaf(h3, wc.w, a2); a3 = fmaf(h3, wd.w, a3);
        zp += 256;
    }
    atomicAdd(&out1acc[(f0 + 0) * BB + lane], a0);
    atomicAdd(&out1acc[(f0 + 1) * BB + lane], a1);
    atomicAdd(&out1acc[(f0 + 2) * BB + lane], a2);
    atomicAdd(&out1acc[(f0 + 3) * BB + lane], a3);
}

// ---------------- tail: bias+leaky on out1acc, then layer2 (100x100) + layer3 (10x100)
__global__ void k_mlp23(const float* __restrict__ out1acc, const float* __restrict__ lb0,
                        const float* __restrict__ lw2, const float* __restrict__ lb2,
                        const float* __restrict__ lw3, const float* __restrict__ lb3,
                        float* __restrict__ out) {
    __shared__ __align__(16) float hin[HID], h3[HID];
    int b = blockIdx.x, tid = threadIdx.x;
    if (tid < HID) hin[tid] = leaky(out1acc[tid * BB + b] + lb0[tid]);
    __syncthreads();
    if (tid < HID) {
        float acc = lb2[tid];
        const float* r = lw2 + tid * HID;
#pragma unroll 4
        for (int k = 0; k < HID; ++k) acc = fmaf(hin[k], r[k], acc);
        h3[tid] = leaky(acc);
    }
    __syncthreads();
    if (tid < NC) {
        float acc = lb3[tid];
        const float* r = lw3 + tid * HID;
#pragma unroll 4
        for (int j = 0; j < HID; ++j) acc = fmaf(h3[j], r[j], acc);
        out[b * NC + tid] = leaky(acc);
    }
}

extern "C" void kernel_launch(void* const* d_in, const int* in_sizes, int n_in,
                              void* d_out, int out_size, void* d_ws, size_t ws_size,
                              hipStream_t stream) {
    const float* in_feat = (const float*)d_in[0];
    const int*   eidx    = (const int*)d_in[1];
    const int*   src     = eidx;
    const int*   dst     = eidx + NE;
    const float* W0  = (const float*)d_in[2];
    const float* b0  = (const float*)d_in[3];
    const float* W1  = (const float*)d_in[4];
    const float* b1  = (const float*)d_in[5];
    const float* lw0 = (const float*)d_in[6];
    const float* lb0 = (const float*)d_in[7];
    const float* lw2 = (const float*)d_in[8];
    const float* lb2 = (const float*)d_in[9];
    const float* lw3 = (const float*)d_in[10];
    const float* lb3 = (const float*)d_in[11];
    float* out = (float*)d_out;

    // workspace carve-up (aligned to 512B)
    char* ws = (char*)d_ws;
    size_t off = 0;
    auto alloc = [&](size_t bytes) -> char* {
        char* p = ws + off;
        off += (bytes + 511) & ~(size_t)511;
        return p;
    };
    // zero-region first: cnt_out | cnt_in | out1acc | s0 | z1 — ONE memset
    char*  zbase   = ws;
    int*   cnt_out = (int*)alloc((size_t)NN * 4);
    int*   cnt_in  = (int*)alloc((size_t)NN * 4);
    float* out1acc = (float*)alloc((size_t)HID * BB * 4);
    float* s0      = (float*)alloc((size_t)NN * BB * 4);
    float* z1      = (float*)alloc((size_t)NN * BB * 4);
    size_t zbytes  = off;
    float* ci      = (float*)alloc((size_t)NN * 4);
    float* y       = (float*)alloc((size_t)NN * BB * 4);

    hipMemsetAsync(zbase, 0, zbytes, stream);

    k_count<<<(NE / 4 + 255) / 256, 256, 0, stream>>>(src, dst, cnt_out, cnt_in);
    k_scat0<<<NE / 16, 256, 0, stream>>>(src, dst, cnt_out, in_feat, s0);
    k_pw<<<(NN * BB) / 256, 256, 0, stream>>>(s0, cnt_out, cnt_in, W0, b0, W1, y, ci);
    k_scat1<<<NE / 16, 256, 0, stream>>>(src, dst, y, z1);
    k_gemm<<<dim3(7, NSPLIT), 256, 0, stream>>>(z1, ci, b1, lw0, out1acc);
    k_mlp23<<<BB, 128, 0, stream>>>(out1acc, lb0, lw2, lb2, lw3, lb3, out);
}

// Round 5
// 217.100 us; speedup vs baseline: 1.1808x; 1.1808x over previous
//
#include <hip/hip_runtime.h>

// Problem constants (from reference setup_inputs)
#define NN 15828      // nodes
#define NE 253248     // edges (divisible by 4)
#define BB 64         // batch == wavefront size
#define HID 100       // hidden
#define NC 10         // classes
#define NEG 0.01f     // leaky slope

__device__ __forceinline__ float leaky(float v) { return v > 0.f ? v : NEG * v; }
__device__ __forceinline__ float rsq(int c) { return rsqrtf((float)(c > 1 ? c : 1)); }

// -------------------------- degree count: 4 edges per thread via int4 loads
__global__ void k_count(const int* __restrict__ src, const int* __restrict__ dst,
                        int* __restrict__ cnt_out, int* __restrict__ cnt_in) {
    int e = (blockIdx.x * blockDim.x + threadIdx.x) * 4;
    if (e < NE) {
        int4 s = *(const int4*)(src + e);
        int4 d = *(const int4*)(dst + e);
        atomicAdd(&cnt_out[s.x], 1); atomicAdd(&cnt_out[s.y], 1);
        atomicAdd(&cnt_out[s.z], 1); atomicAdd(&cnt_out[s.w], 1);
        atomicAdd(&cnt_in[d.x], 1);  atomicAdd(&cnt_in[d.y], 1);
        atomicAdd(&cnt_in[d.z], 1);  atomicAdd(&cnt_in[d.w], 1);
    }
}

// ---- exclusive scan of cnt_in -> rowptr[0..NN], cursor (1 block, 1 barrier)
__global__ void k_scan(const int* __restrict__ cnt, int* __restrict__ rowptr,
                       int* __restrict__ cursor) {
    __shared__ int wsum[4];
    int tid = threadIdx.x;            // 256 threads
    int lane = tid & 63, w = tid >> 6;
    const int PER = (NN + 255) / 256; // 62
    int s = tid * PER, e = min(NN, s + PER);
    int sum = 0;
    for (int i = s; i < e; ++i) sum += cnt[i];
    int v = sum;
    for (int off = 1; off < 64; off <<= 1) {
        int t = __shfl_up(v, off, 64);
        if (lane >= off) v += t;
    }
    if (lane == 63) wsum[w] = v;
    __syncthreads();
    int base = 0;
    for (int i = 0; i < w; ++i) base += wsum[i];
    int run = base + v - sum;         // exclusive prefix for this thread's range
    for (int i = s; i < e; ++i) {
        int c = cnt[i];
        rowptr[i] = run;
        cursor[i] = run;
        run += c;
    }
    if (tid == 255) rowptr[NN] = NE;
}

// -------------------------- CSR fill: 4 edges per thread via int4 loads
__global__ void k_fill(const int* __restrict__ src, const int* __restrict__ dst,
                       int* __restrict__ cursor, int* __restrict__ csr) {
    int e = (blockIdx.x * blockDim.x + threadIdx.x) * 4;
    if (e < NE) {
        int4 s = *(const int4*)(src + e);
        int4 d = *(const int4*)(dst + e);
        csr[atomicAdd(&cursor[d.x], 1)] = s.x;
        csr[atomicAdd(&cursor[d.y], 1)] = s.y;
        csr[atomicAdd(&cursor[d.z], 1)] = s.z;
        csr[atomicAdd(&cursor[d.w], 1)] = s.w;
    }
}

// --- fused conv0: gather feat[src]*rsqrt(deg_out[src]), dst-normalize,
//     conv0 weight/bias/leaky, conv1 weight, conv1 src-scale:
//   s0 = rsq(cnt_in[n]) * sum_{in-edges} feat[src,b]*rsq(cnt_out[src])
//   y[n,b] = rsq(cnt_out[n]) * sum_f leaky(s0*W0[f] + b0[f]) * W1[f]
// one wave per node, lane = batch index
__global__ void k_agg0pw(const int* __restrict__ rowptr, const int* __restrict__ csr,
                         const float* __restrict__ feat,
                         const int* __restrict__ cnt_out, const int* __restrict__ cnt_in,
                         const float* __restrict__ W0, const float* __restrict__ b0,
                         const float* __restrict__ W1, float* __restrict__ y) {
    __shared__ __align__(16) float w0s[HID], b0s[HID], w1s[HID];
    int tid = threadIdx.x;
    if (tid < HID) { w0s[tid] = W0[tid]; b0s[tid] = b0[tid]; w1s[tid] = W1[tid]; }
    __syncthreads();
    int node = (blockIdx.x * blockDim.x + tid) >> 6;   // grid exactly NN/4 blocks
    int lane = tid & 63;
    int k = rowptr[node], kend = rowptr[node + 1];
    float a0 = 0.f, a1 = 0.f, a2 = 0.f, a3 = 0.f;
    // head: reach int4 alignment of csr pointer
    for (; k < kend && (k & 3); ++k) {
        int s = csr[k];
        a0 = fmaf(feat[(s << 6) + lane], rsq(cnt_out[s]), a0);
    }
    for (; k + 3 < kend; k += 4) {
        int4 s4 = *(const int4*)(csr + k);
        float r0 = rsq(cnt_out[s4.x]), r1 = rsq(cnt_out[s4.y]);
        float r2 = rsq(cnt_out[s4.z]), r3 = rsq(cnt_out[s4.w]);
        a0 = fmaf(feat[(s4.x << 6) + lane], r0, a0);
        a1 = fmaf(feat[(s4.y << 6) + lane], r1, a1);
        a2 = fmaf(feat[(s4.z << 6) + lane], r2, a2);
        a3 = fmaf(feat[(s4.w << 6) + lane], r3, a3);
    }
    for (; k < kend; ++k) {
        int s = csr[k];
        a0 = fmaf(feat[(s << 6) + lane], rsq(cnt_out[s]), a0);
    }
    float t = rsq(cnt_in[node]) * ((a0 + a1) + (a2 + a3));
    float acc = 0.f;
#pragma unroll
    for (int f = 0; f < HID; f += 4) {
        float4 w0v = *(const float4*)&w0s[f];
        float4 b0v = *(const float4*)&b0s[f];
        float4 w1v = *(const float4*)&w1s[f];
        float v0 = fmaf(t, w0v.x, b0v.x); v0 = v0 > 0.f ? v0 : NEG * v0; acc = fmaf(v0, w1v.x, acc);
        float v1 = fmaf(t, w0v.y, b0v.y); v1 = v1 > 0.f ? v1 : NEG * v1; acc = fmaf(v1, w1v.y, acc);
        float v2 = fmaf(t, w0v.z, b0v.z); v2 = v2 > 0.f ? v2 : NEG * v2; acc = fmaf(v2, w1v.z, acc);
        float v3 = fmaf(t, w0v.w, b0v.w); v3 = v3 > 0.f ? v3 : NEG * v3; acc = fmaf(v3, w1v.w, acc);
    }
    y[(node << 6) + lane] = acc * rsq(cnt_out[node]);
}

// -------- conv1 aggregation + bias + leaky: h1[n,b] = leaky(rsq(cnt_in)*sum y + b1)
__global__ void k_agg1(const int* __restrict__ rowptr, const int* __restrict__ csr,
                       const float* __restrict__ y, const int* __restrict__ cnt_in,
                       const float* __restrict__ b1, float* __restrict__ h1) {
    int node = (blockIdx.x * blockDim.x + threadIdx.x) >> 6;
    int lane = threadIdx.x & 63;
    int k = rowptr[node], kend = rowptr[node + 1];
    float a0 = 0.f, a1 = 0.f, a2 = 0.f, a3 = 0.f;
    for (; k < kend && (k & 3); ++k) a0 += y[(csr[k] << 6) + lane];
    for (; k + 3 < kend; k += 4) {
        int4 s4 = *(const int4*)(csr + k);
        a0 += y[(s4.x << 6) + lane];
        a1 += y[(s4.y << 6) + lane];
        a2 += y[(s4.z << 6) + lane];
        a3 += y[(s4.w << 6) + lane];
    }
    for (; k < kend; ++k) a0 += y[(csr[k] << 6) + lane];
    float v = fmaf(rsq(cnt_in[node]), (a0 + a1) + (a2 + a3), b1[0]);
    h1[(node << 6) + lane] = leaky(v);
}

// ------- split-K GEMM with atomic epilogue:
//   out1acc[f*64+b] += sum_{n in chunk s} h1[n,b]*lw0[f,n]
// one wave per block; each wave computes 4 consecutive f rows (no idle waves).
// lane = b -> h1 reads coalesced 256B; lw0 read as uniform float4 broadcast.
#define NSPLIT 128
#define NCHUNK 124   // 128*124 = 15872 >= 15828; all chunk lengths divisible by 4
__global__ void k_gemm(const float* __restrict__ h1, const float* __restrict__ lw0,
                       float* __restrict__ out1acc) {
    int lane = threadIdx.x;               // block = 64 threads = 1 wave
    int f0 = blockIdx.x * 4;              // 0,4,...,96  (grid.x = 25)
    int s = blockIdx.y;                   // 0..127
    int n0 = s * NCHUNK;
    int n1 = min(NN, n0 + NCHUNK);
    const float* hp  = h1 + (size_t)n0 * BB + lane;
    const float* w0p = lw0 + (size_t)(f0 + 0) * NN;
    const float* w1p = lw0 + (size_t)(f0 + 1) * NN;
    const float* w2p = lw0 + (size_t)(f0 + 2) * NN;
    const float* w3p = lw0 + (size_t)(f0 + 3) * NN;
    float a0 = 0.f, a1 = 0.f, a2 = 0.f, a3 = 0.f;
    for (int n = n0; n < n1; n += 4) {
        float4 wa = *(const float4*)(w0p + n);
        float4 wb = *(const float4*)(w1p + n);
        float4 wc = *(const float4*)(w2p + n);
        float4 wd = *(const float4*)(w3p + n);
        float h0 = hp[0], h1v = hp[64], h2 = hp[128], h3 = hp[192];
        a0 = fmaf(h0, wa.x, a0); a1 = fmaf(h0, wb.x, a1); a2 = fmaf(h0, wc.x, a2); a3 = fmaf(h0, wd.x, a3);
        a0 = fmaf(h1v, wa.y, a0); a1 = fmaf(h1v, wb.y, a1); a2 = fmaf(h1v, wc.y, a2); a3 = fmaf(h1v, wd.y, a3);
        a0 = fmaf(h2, wa.z, a0); a1 = fmaf(h2, wb.z, a1); a2 = fmaf(h2, wc.z, a2); a3 = fmaf(h2, wd.z, a3);
        a0 = fmaf(h3, wa.w, a0); a1 = fmaf(h3, wb.w, a1); a2 = fmaf(h3, wc.w, a2); a3 = fmaf(h3, wd.w, a3);
        hp += 256;
    }
    atomicAdd(&out1acc[(f0 + 0) * BB + lane], a0);
    atomicAdd(&out1acc[(f0 + 1) * BB + lane], a1);
    atomicAdd(&out1acc[(f0 + 2) * BB + lane], a2);
    atomicAdd(&out1acc[(f0 + 3) * BB + lane], a3);
}

// ---------------- tail: bias+leaky on out1acc, then layer2 (100x100) + layer3 (10x100)
__global__ void k_mlp23(const float* __restrict__ out1acc, const float* __restrict__ lb0,
                        const float* __restrict__ lw2, const float* __restrict__ lb2,
                        const float* __restrict__ lw3, const float* __restrict__ lb3,
                        float* __restrict__ out) {
    __shared__ __align__(16) float hin[HID], h3[HID];
    int b = blockIdx.x, tid = threadIdx.x;
    if (tid < HID) hin[tid] = leaky(out1acc[tid * BB + b] + lb0[tid]);
    __syncthreads();
    if (tid < HID) {
        float acc = lb2[tid];
        const float* r = lw2 + tid * HID;
#pragma unroll 4
        for (int k = 0; k < HID; ++k) acc = fmaf(hin[k], r[k], acc);
        h3[tid] = leaky(acc);
    }
    __syncthreads();
    if (tid < NC) {
        float acc = lb3[tid];
        const float* r = lw3 + tid * HID;
#pragma unroll 4
        for (int j = 0; j < HID; ++j) acc = fmaf(h3[j], r[j], acc);
        out[b * NC + tid] = leaky(acc);
    }
}

extern "C" void kernel_launch(void* const* d_in, const int* in_sizes, int n_in,
                              void* d_out, int out_size, void* d_ws, size_t ws_size,
                              hipStream_t stream) {
    const float* in_feat = (const float*)d_in[0];
    const int*   eidx    = (const int*)d_in[1];
    const int*   src     = eidx;
    const int*   dst     = eidx + NE;
    const float* W0  = (const float*)d_in[2];
    const float* b0  = (const float*)d_in[3];
    const float* W1  = (const float*)d_in[4];
    const float* b1  = (const float*)d_in[5];
    const float* lw0 = (const float*)d_in[6];
    const float* lb0 = (const float*)d_in[7];
    const float* lw2 = (const float*)d_in[8];
    const float* lb2 = (const float*)d_in[9];
    const float* lw3 = (const float*)d_in[10];
    const float* lb3 = (const float*)d_in[11];
    float* out = (float*)d_out;

    // workspace carve-up (aligned to 512B)
    char* ws = (char*)d_ws;
    size_t off = 0;
    auto alloc = [&](size_t bytes) -> char* {
        char* p = ws + off;
        off += (bytes + 511) & ~(size_t)511;
        return p;
    };
    // zero-region first: cnt_out | cnt_in | out1acc — ONE memset
    char*  zbase   = ws;
    int*   cnt_out = (int*)alloc((size_t)NN * 4);
    int*   cnt_in  = (int*)alloc((size_t)NN * 4);
    float* out1acc = (float*)alloc((size_t)HID * BB * 4);
    size_t zbytes  = off;
    int* rowptr  = (int*)alloc((size_t)(NN + 1) * 4);
    int* cursor  = (int*)alloc((size_t)NN * 4);
    int* csr     = (int*)alloc((size_t)NE * 4);
    float* y     = (float*)alloc((size_t)NN * BB * 4);
    float* h1    = (float*)alloc((size_t)NN * BB * 4);

    hipMemsetAsync(zbase, 0, zbytes, stream);

    k_count<<<(NE / 4 + 255) / 256, 256, 0, stream>>>(src, dst, cnt_out, cnt_in);
    k_scan<<<1, 256, 0, stream>>>(cnt_in, rowptr, cursor);
    k_fill<<<(NE / 4 + 255) / 256, 256, 0, stream>>>(src, dst, cursor, csr);
    k_agg0pw<<<NN / 4, 256, 0, stream>>>(rowptr, csr, in_feat, cnt_out, cnt_in, W0, b0, W1, y);
    k_agg1<<<NN / 4, 256, 0, stream>>>(rowptr, csr, y, cnt_in, b1, h1);
    k_gemm<<<dim3(25, NSPLIT), 64, 0, stream>>>(h1, lw0, out1acc);
    k_mlp23<<<BB, 128, 0, stream>>>(out1acc, lb0, lw2, lb2, lw3, lb3, out);
}

// Round 7
// 214.016 us; speedup vs baseline: 1.1979x; 1.0144x over previous
//
#include <hip/hip_runtime.h>

// Problem constants (from reference setup_inputs)
#define NN 15828      // nodes
#define NE 253248     // edges (divisible by 4)
#define BB 64         // batch == wavefront size
#define HID 100       // hidden
#define NC 10         // classes
#define NEG 0.01f     // leaky slope

__device__ __forceinline__ float leaky(float v) { return v > 0.f ? v : NEG * v; }
__device__ __forceinline__ float rsq(int c) { return rsqrtf((float)(c > 1 ? c : 1)); }

// -------------------------- degree count: 4 edges per thread via int4 loads
__global__ void k_count(const int* __restrict__ src, const int* __restrict__ dst,
                        int* __restrict__ cnt_out, int* __restrict__ cnt_in) {
    int e = (blockIdx.x * blockDim.x + threadIdx.x) * 4;
    if (e < NE) {
        int4 s = *(const int4*)(src + e);
        int4 d = *(const int4*)(dst + e);
        atomicAdd(&cnt_out[s.x], 1); atomicAdd(&cnt_out[s.y], 1);
        atomicAdd(&cnt_out[s.z], 1); atomicAdd(&cnt_out[s.w], 1);
        atomicAdd(&cnt_in[d.x], 1);  atomicAdd(&cnt_in[d.y], 1);
        atomicAdd(&cnt_in[d.z], 1);  atomicAdd(&cnt_in[d.w], 1);
    }
}

// ---- block 0: exclusive scan of cnt_in -> rowptr/cursor (1 barrier);
//      all blocks: xf[n,b] = feat[n,b] * rsqrt(deg_out[n])  (grid-stride)
// grid = NN*BB/256 = 3957 blocks
__global__ void k_scanxf(const int* __restrict__ cnt_in, const int* __restrict__ cnt_out,
                         const float* __restrict__ feat,
                         int* __restrict__ rowptr, int* __restrict__ cursor,
                         float* __restrict__ xf) {
    int tid = threadIdx.x;
    if (blockIdx.x == 0) {
        __shared__ int wsum[4];
        int lane = tid & 63, w = tid >> 6;
        const int PER = (NN + 255) / 256; // 62
        int s = tid * PER, e = min(NN, s + PER);
        int sum = 0;
        for (int i = s; i < e; ++i) sum += cnt_in[i];
        int v = sum;
        for (int off = 1; off < 64; off <<= 1) {
            int t = __shfl_up(v, off, 64);
            if (lane >= off) v += t;
        }
        if (lane == 63) wsum[w] = v;
        __syncthreads();
        int base = 0;
        for (int i = 0; i < w; ++i) base += wsum[i];
        int run = base + v - sum;         // exclusive prefix for this thread's range
        for (int i = s; i < e; ++i) {
            int c = cnt_in[i];
            rowptr[i] = run;
            cursor[i] = run;
            run += c;
        }
        if (tid == 255) rowptr[NN] = NE;
    }
    int i = blockIdx.x * blockDim.x + tid;  // grid sized exactly NN*BB/256
    xf[i] = feat[i] * rsq(cnt_out[i >> 6]);
}

// -------------------------- CSR fill: 4 edges per thread via int4 loads
__global__ void k_fill(const int* __restrict__ src, const int* __restrict__ dst,
                       int* __restrict__ cursor, int* __restrict__ csr) {
    int e = (blockIdx.x * blockDim.x + threadIdx.x) * 4;
    if (e < NE) {
        int4 s = *(const int4*)(src + e);
        int4 d = *(const int4*)(dst + e);
        csr[atomicAdd(&cursor[d.x], 1)] = s.x;
        csr[atomicAdd(&cursor[d.y], 1)] = s.y;
        csr[atomicAdd(&cursor[d.z], 1)] = s.z;
        csr[atomicAdd(&cursor[d.w], 1)] = s.w;
    }
}

// --- fused conv0 gather + pointwise; one wave per node, lane = batch.
//   s0 = rsq(cnt_in[n]) * sum_{in-edges} xf[src,b]
//   y[n,b] = rsq(cnt_out[n]) * sum_f leaky(s0*W0[f] + b0[f]) * W1[f]
// 8-way ILP in the gather: 8 independent 256B loads in flight per iteration.
__global__ void k_agg0pw(const int* __restrict__ rowptr, const int* __restrict__ csr,
                         const float* __restrict__ xf,
                         const int* __restrict__ cnt_out, const int* __restrict__ cnt_in,
                         const float* __restrict__ W0, const float* __restrict__ b0,
                         const float* __restrict__ W1, float* __restrict__ y) {
    __shared__ __align__(16) float w0s[HID], b0s[HID], w1s[HID];
    int tid = threadIdx.x;
    if (tid < HID) { w0s[tid] = W0[tid]; b0s[tid] = b0[tid]; w1s[tid] = W1[tid]; }
    __syncthreads();
    int node = (blockIdx.x * blockDim.x + tid) >> 6;   // grid exactly NN/4 blocks
    int lane = tid & 63;
    int k = rowptr[node], kend = rowptr[node + 1];
    float a0 = 0.f, a1 = 0.f, a2 = 0.f, a3 = 0.f;
    float a4 = 0.f, a5 = 0.f, a6 = 0.f, a7 = 0.f;
    for (; k < kend && (k & 3); ++k) a0 += xf[(csr[k] << 6) + lane];
    for (; k + 7 < kend; k += 8) {
        int4 sa = *(const int4*)(csr + k);
        int4 sb = *(const int4*)(csr + k + 4);
        a0 += xf[(sa.x << 6) + lane];
        a1 += xf[(sa.y << 6) + lane];
        a2 += xf[(sa.z << 6) + lane];
        a3 += xf[(sa.w << 6) + lane];
        a4 += xf[(sb.x << 6) + lane];
        a5 += xf[(sb.y << 6) + lane];
        a6 += xf[(sb.z << 6) + lane];
        a7 += xf[(sb.w << 6) + lane];
    }
    if (k + 3 < kend) {
        int4 sa = *(const int4*)(csr + k);
        a0 += xf[(sa.x << 6) + lane];
        a1 += xf[(sa.y << 6) + lane];
        a2 += xf[(sa.z << 6) + lane];
        a3 += xf[(sa.w << 6) + lane];
        k += 4;
    }
    for (; k < kend; ++k) a0 += xf[(csr[k] << 6) + lane];
    float t = rsq(cnt_in[node]) * (((a0 + a1) + (a2 + a3)) + ((a4 + a5) + (a6 + a7)));
    float acc = 0.f;
#pragma unroll
    for (int f = 0; f < HID; f += 4) {
        float4 w0v = *(const float4*)&w0s[f];
        float4 b0v = *(const float4*)&b0s[f];
        float4 w1v = *(const float4*)&w1s[f];
        float v0 = fmaf(t, w0v.x, b0v.x); v0 = v0 > 0.f ? v0 : NEG * v0; acc = fmaf(v0, w1v.x, acc);
        float v1 = fmaf(t, w0v.y, b0v.y); v1 = v1 > 0.f ? v1 : NEG * v1; acc = fmaf(v1, w1v.y, acc);
        float v2 = fmaf(t, w0v.z, b0v.z); v2 = v2 > 0.f ? v2 : NEG * v2; acc = fmaf(v2, w1v.z, acc);
        float v3 = fmaf(t, w0v.w, b0v.w); v3 = v3 > 0.f ? v3 : NEG * v3; acc = fmaf(v3, w1v.w, acc);
    }
    y[(node << 6) + lane] = acc * rsq(cnt_out[node]);
}

// -------- conv1 gather + bias + leaky: h1[n,b] = leaky(rsq(cnt_in)*sum y + b1)
__global__ void k_agg1(const int* __restrict__ rowptr, const int* __restrict__ csr,
                       const float* __restrict__ y, const int* __restrict__ cnt_in,
                       const float* __restrict__ b1, float* __restrict__ h1) {
    int node = (blockIdx.x * blockDim.x + threadIdx.x) >> 6;
    int lane = threadIdx.x & 63;
    int k = rowptr[node], kend = rowptr[node + 1];
    float a0 = 0.f, a1 = 0.f, a2 = 0.f, a3 = 0.f;
    float a4 = 0.f, a5 = 0.f, a6 = 0.f, a7 = 0.f;
    for (; k < kend && (k & 3); ++k) a0 += y[(csr[k] << 6) + lane];
    for (; k + 7 < kend; k += 8) {
        int4 sa = *(const int4*)(csr + k);
        int4 sb = *(const int4*)(csr + k + 4);
        a0 += y[(sa.x << 6) + lane];
        a1 += y[(sa.y << 6) + lane];
        a2 += y[(sa.z << 6) + lane];
        a3 += y[(sa.w << 6) + lane];
        a4 += y[(sb.x << 6) + lane];
        a5 += y[(sb.y << 6) + lane];
        a6 += y[(sb.z << 6) + lane];
        a7 += y[(sb.w << 6) + lane];
    }
    if (k + 3 < kend) {
        int4 sa = *(const int4*)(csr + k);
        a0 += y[(sa.x << 6) + lane];
        a1 += y[(sa.y << 6) + lane];
        a2 += y[(sa.z << 6) + lane];
        a3 += y[(sa.w << 6) + lane];
        k += 4;
    }
    for (; k < kend; ++k) a0 += y[(csr[k] << 6) + lane];
    float s = ((a0 + a1) + (a2 + a3)) + ((a4 + a5) + (a6 + a7));
    float v = fmaf(rsq(cnt_in[node]), s, b1[0]);
    h1[(node << 6) + lane] = leaky(v);
}

// ------- split-K GEMM with atomic epilogue:
//   out1acc[f*64+b] += sum_{n in chunk s} h1[n,b]*lw0[f,n]
// one wave per block; each wave computes 4 consecutive f rows (no idle waves).
#define NSPLIT 128
#define NCHUNK 124   // 128*124 = 15872 >= 15828; all chunk lengths divisible by 4
__global__ void k_gemm(const float* __restrict__ h1, const float* __restrict__ lw0,
                       float* __restrict__ out1acc) {
    int lane = threadIdx.x;               // block = 64 threads = 1 wave
    int f0 = blockIdx.x * 4;              // 0,4,...,96  (grid.x = 25)
    int s = blockIdx.y;                   // 0..127
    int n0 = s * NCHUNK;
    int n1 = min(NN, n0 + NCHUNK);
    const float* hp  = h1 + (size_t)n0 * BB + lane;
    const float* w0p = lw0 + (size_t)(f0 + 0) * NN;
    const float* w1p = lw0 + (size_t)(f0 + 1) * NN;
    const float* w2p = lw0 + (size_t)(f0 + 2) * NN;
    const float* w3p = lw0 + (size_t)(f0 + 3) * NN;
    float a0 = 0.f, a1 = 0.f, a2 = 0.f, a3 = 0.f;
    for (int n = n0; n < n1; n += 4) {
        float4 wa = *(const float4*)(w0p + n);
        float4 wb = *(const float4*)(w1p + n);
        float4 wc = *(const float4*)(w2p + n);
        float4 wd = *(const float4*)(w3p + n);
        float h0 = hp[0], h1v = hp[64], h2 = hp[128], h3 = hp[192];
        a0 = fmaf(h0, wa.x, a0); a1 = fmaf(h0, wb.x, a1); a2 = fmaf(h0, wc.x, a2); a3 = fmaf(h0, wd.x, a3);
        a0 = fmaf(h1v, wa.y, a0); a1 = fmaf(h1v, wb.y, a1); a2 = fmaf(h1v, wc.y, a2); a3 = fmaf(h1v, wd.y, a3);
        a0 = fmaf(h2, wa.z, a0); a1 = fmaf(h2, wb.z, a1); a2 = fmaf(h2, wc.z, a2); a3 = fmaf(h2, wd.z, a3);
        a0 = fmaf(h3, wa.w, a0); a1 = fmaf(h3, wb.w, a1); a2 = fmaf(h3, wc.w, a2); a3 = fmaf(h3, wd.w, a3);
        hp += 256;
    }
    atomicAdd(&out1acc[(f0 + 0) * BB + lane], a0);
    atomicAdd(&out1acc[(f0 + 1) * BB + lane], a1);
    atomicAdd(&out1acc[(f0 + 2) * BB + lane], a2);
    atomicAdd(&out1acc[(f0 + 3) * BB + lane], a3);
}

// ---------------- tail: bias+leaky on out1acc, then layer2 (100x100) + layer3 (10x100)
__global__ void k_mlp23(const float* __restrict__ out1acc, const float* __restrict__ lb0,
                        const float* __restrict__ lw2, const float* __restrict__ lb2,
                        const float* __restrict__ lw3, const float* __restrict__ lb3,
                        float* __restrict__ out) {
    __shared__ __align__(16) float hin[HID], h3[HID];
    int b = blockIdx.x, tid = threadIdx.x;
    if (tid < HID) hin[tid] = leaky(out1acc[tid * BB + b] + lb0[tid]);
    __syncthreads();
    if (tid < HID) {
        float acc = lb2[tid];
        const float* r = lw2 + tid * HID;
#pragma unroll 4
        for (int k = 0; k < HID; ++k) acc = fmaf(hin[k], r[k], acc);
        h3[tid] = leaky(acc);
    }
    __syncthreads();
    if (tid < NC) {
        float acc = lb3[tid];
        const float* r = lw3 + tid * HID;
#pragma unroll 4
        for (int j = 0; j < HID; ++j) acc = fmaf(h3[j], r[j], acc);
        out[b * NC + tid] = leaky(acc);
    }
}

extern "C" void kernel_launch(void* const* d_in, const int* in_sizes, int n_in,
                              void* d_out, int out_size, void* d_ws, size_t ws_size,
                              hipStream_t stream) {
    const float* in_feat = (const float*)d_in[0];
    const int*   eidx    = (const int*)d_in[1];
    const int*   src     = eidx;
    const int*   dst     = eidx + NE;
    const float* W0  = (const float*)d_in[2];
    const float* b0  = (const float*)d_in[3];
    const float* W1  = (const float*)d_in[4];
    const float* b1  = (const float*)d_in[5];
    const float* lw0 = (const float*)d_in[6];
    const float* lb0 = (const float*)d_in[7];
    const float* lw2 = (const float*)d_in[8];
    const float* lb2 = (const float*)d_in[9];
    const float* lw3 = (const float*)d_in[10];
    const float* lb3 = (const float*)d_in[11];
    float* out = (float*)d_out;

    // workspace carve-up (aligned to 512B)
    char* ws = (char*)d_ws;
    size_t off = 0;
    auto alloc = [&](size_t bytes) -> char* {
        char* p = ws + off;
        off += (bytes + 511) & ~(size_t)511;
        return p;
    };
    // zero-region first: cnt_out | cnt_in | out1acc — ONE memset
    char*  zbase   = ws;
    int*   cnt_out = (int*)alloc((size_t)NN * 4);
    int*   cnt_in  = (int*)alloc((size_t)NN * 4);
    float* out1acc = (float*)alloc((size_t)HID * BB * 4);
    size_t zbytes  = off;
    int* rowptr  = (int*)alloc((size_t)(NN + 1) * 4);
    int* cursor  = (int*)alloc((size_t)NN * 4);
    int* csr     = (int*)alloc((size_t)NE * 4);
    float* xf    = (float*)alloc((size_t)NN * BB * 4);
    float* y     = (float*)alloc((size_t)NN * BB * 4);
    float* h1    = (float*)alloc((size_t)NN * BB * 4);

    hipMemsetAsync(zbase, 0, zbytes, stream);

    k_count<<<(NE / 4 + 255) / 256, 256, 0, stream>>>(src, dst, cnt_out, cnt_in);
    k_scanxf<<<(NN * BB) / 256, 256, 0, stream>>>(cnt_in, cnt_out, in_feat, rowptr, cursor, xf);
    k_fill<<<(NE / 4 + 255) / 256, 256, 0, stream>>>(src, dst, cursor, csr);
    k_agg0pw<<<NN / 4, 256, 0, stream>>>(rowptr, csr, xf, cnt_out, cnt_in, W0, b0, W1, y);
    k_agg1<<<NN / 4, 256, 0, stream>>>(rowptr, csr, y, cnt_in, b1, h1);
    k_gemm<<<dim3(25, NSPLIT), 64, 0, stream>>>(h1, lw0, out1acc);
    k_mlp23<<<BB, 128, 0, stream>>>(out1acc, lb0, lw2, lb2, lw3, lb3, out);
}